// Round 2
// baseline (488.195 us; speedup 1.0000x reference)
//
#include <hip/hip_runtime.h>
#include <math.h>

#define NROWS 4096
#define NCOLS 16384
#define NGRP  512                   // NCOLS / 32
#define TOTAL_ELEMS (67108864ULL)   // NROWS * NCOLS
#define TOTAL4      (16777216ULL)   // TOTAL_ELEMS / 4

// Scratch strategy: NO d_ws, NO hipMemsetAsync (both were abort suspects).
// The 1024-float output tail (eps_eff[512], e_base[512]) doubles as the
// per-group max-abs accumulator during pass 1, then setup_kernel overwrites
// it with the real outputs before quant_kernel reads it.

__global__ void init_kernel(unsigned int* __restrict__ gmax) {
    gmax[threadIdx.x] = 0u;   // 512 threads, 1 block
}

// Pass 1: per-group max(|w|). Groups are column-blocks of 32; every aligned
// float4 lies inside one group and 8 consecutive lanes (32 floats) share a
// group. shfl-xor reduce the 8-lane cluster, one LDS atomicMax per cluster,
// per-block flush to global. abs-float bits compare correctly as uint.
__global__ void maxabs_kernel(const float4* __restrict__ w,
                              unsigned int* __restrict__ gmax) {
    __shared__ unsigned int smax[NGRP];
    for (int i = threadIdx.x; i < NGRP; i += blockDim.x) smax[i] = 0u;
    __syncthreads();

    const size_t stride = (size_t)gridDim.x * blockDim.x;
    for (size_t i = (size_t)blockIdx.x * blockDim.x + threadIdx.x;
         i < TOTAL4; i += stride) {
        float4 v = w[i];
        float m = fmaxf(fmaxf(fabsf(v.x), fabsf(v.y)),
                        fmaxf(fabsf(v.z), fabsf(v.w)));
        m = fmaxf(m, __shfl_xor(m, 1, 64));
        m = fmaxf(m, __shfl_xor(m, 2, 64));
        m = fmaxf(m, __shfl_xor(m, 4, 64));
        if ((threadIdx.x & 7) == 0) {
            int g = (int)((i & 4095) >> 3);   // ((4i) % 16384) / 32
            atomicMax(&smax[g], __float_as_uint(m));
        }
    }
    __syncthreads();
    for (int g = threadIdx.x; g < NGRP; g += blockDim.x)
        if (smax[g]) atomicMax(&gmax[g], smax[g]);
}

// Pass 1.5: read gmax bits from the tail, overwrite tail with the final
// eps_eff (tail[0..512)) and e_base (tail[512..1024)) outputs.
// frexpf gives exact floor(log2(ma)) = ex-1; scale 2^e reconstructed later.
__global__ void setup_kernel(const float* __restrict__ eps_param,
                             const float* __restrict__ delta,
                             float* __restrict__ tail) {
    int g = threadIdx.x;   // exactly NGRP threads, 1 block
    float ma = __uint_as_float(((const unsigned int*)tail)[g]);
    float e = 0.f;
    if (ma > 0.f) {
        int ex;
        (void)frexpf(ma, &ex);      // ma = m * 2^ex, m in [0.5, 1)
        e = (float)(ex - 1);        // floor(log2(ma)) exactly
    }
    float eps = 0.5f * tanhf(eps_param[g]);
    float ee  = fminf(fmaxf(eps + delta[g], -0.5f), 0.5f);
    tail[g]        = ee;    // output: eps_eff
    tail[NGRP + g] = e;     // output: e_base
}

__device__ __forceinline__ float quant1(float a, float s, float inv, float ee) {
    float r  = fminf(fabsf(a) * inv, 1.f);        // clip(|w|/s, 0, 1) — exact mul
    float sh = fminf(fmaxf(r + ee, 0.f), 1.f);    // clip(+eps_eff, 0, 1)
    float mq = rintf(sh * 8.f) * 0.125f;          // round-half-even = np.round
    float q  = copysignf(s * mq, a);
    return (a == 0.f) ? 0.f : q;                  // jnp.sign(0) == 0
}

// Pass 2: elementwise quantization, float4 in / float4 out. Per-group scale
// rebuilt from e_base by exponent bit-packing (e is a small integer).
__global__ void quant_kernel(const float4* __restrict__ w,
                             const float* __restrict__ tail,
                             float4* __restrict__ out) {
    const size_t stride = (size_t)gridDim.x * blockDim.x;
    for (size_t i = (size_t)blockIdx.x * blockDim.x + threadIdx.x;
         i < TOTAL4; i += stride) {
        int g = (int)((i & 4095) >> 3);
        float ee = tail[g];
        int   ei = (int)tail[NGRP + g];
        float s   = __uint_as_float((unsigned)(ei + 127) << 23);  // 2^e  (exact)
        float inv = __uint_as_float((unsigned)(127 - ei) << 23);  // 2^-e (exact)
        float4 v = w[i];
        float4 o;
        o.x = quant1(v.x, s, inv, ee);
        o.y = quant1(v.y, s, inv, ee);
        o.z = quant1(v.z, s, inv, ee);
        o.w = quant1(v.w, s, inv, ee);
        out[i] = o;
    }
}

extern "C" void kernel_launch(void* const* d_in, const int* in_sizes, int n_in,
                              void* d_out, int out_size, void* d_ws, size_t ws_size,
                              hipStream_t stream) {
    const float* weight    = (const float*)d_in[0];
    const float* eps_param = (const float*)d_in[1];
    const float* delta     = (const float*)d_in[2];
    float* out  = (float*)d_out;
    float* tail = out + TOTAL_ELEMS;   // 1024 floats: gmax scratch -> outputs

    init_kernel<<<1, NGRP, 0, stream>>>((unsigned int*)tail);
    maxabs_kernel<<<4096, 256, 0, stream>>>((const float4*)weight,
                                            (unsigned int*)tail);
    setup_kernel<<<1, NGRP, 0, stream>>>(eps_param, delta, tail);
    quant_kernel<<<8192, 256, 0, stream>>>((const float4*)weight, tail,
                                           (float4*)out);
}

// Round 4
// 478.614 us; speedup vs baseline: 1.0200x; 1.0200x over previous
//
#include <hip/hip_runtime.h>
#include <math.h>

#define NROWS 4096
#define NCOLS 16384
#define NGRP  512                   // NCOLS / 32
#define TOTAL_ELEMS (67108864ULL)   // NROWS * NCOLS
#define TOTAL4      (16777216ULL)   // TOTAL_ELEMS / 4

typedef float nfloat4 __attribute__((ext_vector_type(4)));  // native vec for nt-store

// Key invariant exploited throughout: grid strides are multiples of 4096
// float4s (= one row of 16384 floats), so each thread's group index
// g = ((4*i) % 16384) / 32 = (i & 4095) >> 3 is LOOP-INVARIANT.

__global__ void init_kernel(unsigned int* __restrict__ gmax) {
    gmax[threadIdx.x] = 0u;   // 512 threads, 1 block
}

// Pass 1: per-group max(|w|). Each thread accumulates a private max over all
// its (same-group) iterations — no per-iter shuffles/atomics. Then one
// 8-lane shfl-xor cluster reduce, one LDS atomic per cluster, and a
// per-block flush (only ~32 distinct groups per block are nonzero).
__global__ void maxabs_kernel(const float4* __restrict__ w,
                              unsigned int* __restrict__ gmax) {
    __shared__ unsigned int smax[NGRP];
    for (int i = threadIdx.x; i < NGRP; i += blockDim.x) smax[i] = 0u;
    __syncthreads();

    const size_t tid0   = (size_t)blockIdx.x * blockDim.x + threadIdx.x;
    const size_t stride = (size_t)gridDim.x * blockDim.x;   // ≡ 0 mod 4096
    const int g = (int)((tid0 & 4095) >> 3);                // loop-invariant

    float m = 0.f;
    for (size_t i = tid0; i < TOTAL4; i += stride) {
        float4 v = w[i];
        m = fmaxf(m, fmaxf(fmaxf(fabsf(v.x), fabsf(v.y)),
                           fmaxf(fabsf(v.z), fabsf(v.w))));
    }
    // 8 consecutive lanes share g (blocks are 256-aligned in tid)
    m = fmaxf(m, __shfl_xor(m, 1, 64));
    m = fmaxf(m, __shfl_xor(m, 2, 64));
    m = fmaxf(m, __shfl_xor(m, 4, 64));
    if ((threadIdx.x & 7) == 0)
        atomicMax(&smax[g], __float_as_uint(m));

    __syncthreads();
    for (int j = threadIdx.x; j < NGRP; j += blockDim.x)
        if (smax[j]) atomicMax(&gmax[j], smax[j]);
}

// Pass 1.5: read gmax bits from the output tail, overwrite tail with the
// final eps_eff (tail[0..512)) and e_base (tail[512..1024)) outputs.
__global__ void setup_kernel(const float* __restrict__ eps_param,
                             const float* __restrict__ delta,
                             float* __restrict__ tail) {
    int g = threadIdx.x;   // exactly NGRP threads, 1 block
    float ma = __uint_as_float(((const unsigned int*)tail)[g]);
    float e = 0.f;
    if (ma > 0.f) {
        int ex;
        (void)frexpf(ma, &ex);      // ma = m * 2^ex, m in [0.5, 1)
        e = (float)(ex - 1);        // floor(log2(ma)) exactly
    }
    float eps = 0.5f * tanhf(eps_param[g]);
    float ee  = fminf(fmaxf(eps + delta[g], -0.5f), 0.5f);
    tail[g]        = ee;    // output: eps_eff
    tail[NGRP + g] = e;     // output: e_base
}

__device__ __forceinline__ float quant1(float a, float s, float inv, float ee) {
    float r  = fminf(fabsf(a) * inv, 1.f);        // clip(|w|/s,0,1) — exact mul
    float sh = fminf(fmaxf(r + ee, 0.f), 1.f);    // clip(+eps_eff, 0, 1)
    float mq = rintf(sh * 8.f) * 0.125f;          // round-half-even = np.round
    float q  = copysignf(s * mq, a);
    return (a == 0.f) ? 0.f : q;                  // jnp.sign(0) == 0
}

// Pass 2: elementwise quantization. Per-thread scalars (s, inv, ee) hoisted
// out of the loop (g loop-invariant). Nontemporal stores: out is
// write-once, never re-read — don't pollute L2/L3.
__global__ void quant_kernel(const float4* __restrict__ w,
                             const float* __restrict__ tail,
                             float4* __restrict__ out) {
    const size_t tid0   = (size_t)blockIdx.x * blockDim.x + threadIdx.x;
    const size_t stride = (size_t)gridDim.x * blockDim.x;   // ≡ 0 mod 4096
    const int g = (int)((tid0 & 4095) >> 3);                // loop-invariant

    const float ee = tail[g];
    const int   ei = (int)tail[NGRP + g];
    const float s   = __uint_as_float((unsigned)(ei + 127) << 23);  // 2^e
    const float inv = __uint_as_float((unsigned)(127 - ei) << 23);  // 2^-e

    for (size_t i = tid0; i < TOTAL4; i += stride) {
        float4 v = w[i];
        nfloat4 o;
        o.x = quant1(v.x, s, inv, ee);
        o.y = quant1(v.y, s, inv, ee);
        o.z = quant1(v.z, s, inv, ee);
        o.w = quant1(v.w, s, inv, ee);
        __builtin_nontemporal_store(o, (nfloat4*)&out[i]);
    }
}

extern "C" void kernel_launch(void* const* d_in, const int* in_sizes, int n_in,
                              void* d_out, int out_size, void* d_ws, size_t ws_size,
                              hipStream_t stream) {
    const float* weight    = (const float*)d_in[0];
    const float* eps_param = (const float*)d_in[1];
    const float* delta     = (const float*)d_in[2];
    float* out  = (float*)d_out;
    float* tail = out + TOTAL_ELEMS;   // 1024 floats: gmax scratch -> outputs

    init_kernel<<<1, NGRP, 0, stream>>>((unsigned int*)tail);
    maxabs_kernel<<<2048, 256, 0, stream>>>((const float4*)weight,
                                            (unsigned int*)tail);
    setup_kernel<<<1, NGRP, 0, stream>>>(eps_param, delta, tail);
    quant_kernel<<<8192, 256, 0, stream>>>((const float4*)weight, tail,
                                           (float4*)out);
}